// Round 5
// baseline (541.490 us; speedup 1.0000x reference)
//
#include <hip/hip_runtime.h>
#include <hip/hip_bf16.h>

// INPUTS/OUTPUT ARE FLOAT32. R1/R3/R4 NaN'd by reading them as bf16
// (f32 low-mantissa halves decode to 2^±100-scale bf16 -> d2 overflow ->
// inf*0 = NaN). R2's pass came from its f32-specialized kernels (runtime
// sniff); this is that path, de-templated. Do NOT cast d_in to bf16.

#define NTOT 2048
#define MTOT 2048
#define MSPLIT 32
#define MCHUNK 64   // == per-block m range: single staging chunk

typedef short bf16x8 __attribute__((ext_vector_type(8)));
typedef float f32x4  __attribute__((ext_vector_type(4)));
typedef int   i32x4  __attribute__((ext_vector_type(4)));

// exp(x) = 2^(x*log2e); sigmoid(x) = 1/(1+2^(-x*log2e))
#define NL2E (-1.4426950408889634f)
// exp(-d2/5) = 2^(d2 * -log2e/5)
#define C1E  (-0.2885390081777927f)

__device__ __forceinline__ float fast_exp2(float x) {
#if __has_builtin(__builtin_amdgcn_exp2f)
  return __builtin_amdgcn_exp2f(x);
#else
  return __exp2f(x);
#endif
}
__device__ __forceinline__ float fast_rcp(float x) {
#if __has_builtin(__builtin_amdgcn_rcpf)
  return __builtin_amdgcn_rcpf(x);
#else
  return 1.0f / x;
#endif
}
__device__ __forceinline__ float fast_rsq(float x) {
#if __has_builtin(__builtin_amdgcn_rsqf)
  return __builtin_amdgcn_rsqf(x);
#else
  return rsqrtf(x);
#endif
}

// f32 -> bf16 raw bits, round-to-nearest-even (for MFMA B fragments)
__device__ __forceinline__ short to_bf16_rne(float x) {
  union { float f; unsigned u; } v; v.f = x;
  unsigned r = v.u + 0x7FFFu + ((v.u >> 16) & 1u);
  return (short)(r >> 16);
}

// pack two f32 -> two bf16 (round-half-up) in one u32 (lo in low half).
// R2-proven path (add 0x8000 + v_perm byte-select of the two high halves).
__device__ __forceinline__ unsigned pack_bf16_rn(float lo, float hi) {
  union { float f; unsigned u; } a, b;
  a.f = lo; b.f = hi;
  unsigned au = a.u + 0x8000u, bu = b.u + 0x8000u;
#if __has_builtin(__builtin_amdgcn_perm)
  return __builtin_amdgcn_perm(bu, au, 0x07060302u);
#else
  return (au >> 16) | (bu & 0xffff0000u);
#endif
}

// ---------------------------------------------------------------------------
// Edge phase: per wave, 16 n-rows; loop over this block's 64-m range.
// For each m: edge feats -> 4->64 MLP+silu (VALU, directly in A-frag layout)
// -> 64->64 via 8x mfma_16x16x32_bf16 -> sigmoid -> accumulate num/den in regs
// -> atomicAdd partials. Grid: (NTOT/64) * MSPLIT = 1024 blocks of 256.
// ---------------------------------------------------------------------------
__global__ __launch_bounds__(256, 4)
void edge_kernel(const float* __restrict__ h_l,
                 const float* __restrict__ x_l,
                 const float* __restrict__ h_r,
                 const float* __restrict__ x_r,
                 const float* __restrict__ W1,
                 const float* __restrict__ b1,
                 const float* __restrict__ W2,
                 const float* __restrict__ b2,
                 float* __restrict__ num_g,
                 float* __restrict__ den_g) {
  __shared__ float hr_s[MCHUNK][64];  // h_r chunk (16 KB)
  __shared__ float xr_s[MCHUNK][8];   // x_r(3), r_p(3), pad (2 KB)

  const int tid  = threadIdx.x;
  const int wave = tid >> 6;
  const int lane = tid & 63;
  const int l15  = lane & 15;
  const int quad = lane >> 4;

  const int nblk   = blockIdx.x / MSPLIT;
  const int msplit = blockIdx.x % MSPLIT;
  const int n0     = nblk * 64 + wave * 16;
  const int mBase  = msplit * MCHUNK;

  // per-lane A-row n
  const int nA = n0 + l15;
  const float xl0 = x_l[nA * 3 + 0];
  const float xl1 = x_l[nA * 3 + 1];
  const float xl2 = x_l[nA * 3 + 2];
  const float lp0 = h_l[nA * 64 + 61];
  const float lp1 = h_l[nA * 64 + 62];
  const float lp2 = h_l[nA * 64 + 63];

  // layer-1 weights for this lane's 16 h1 columns (h1 = quad*8+j and 32+quad*8+j)
  float w1d[16], w1h[16], w1y[16], b1p[16];
#pragma unroll
  for (int j = 0; j < 8; ++j) {
    const int ha = quad * 8 + j, hb = 32 + quad * 8 + j;
    w1d[j] = W1[0 * 64 + ha];   w1d[8 + j] = W1[0 * 64 + hb];
    w1h[j] = W1[1 * 64 + ha];   w1h[8 + j] = W1[1 * 64 + hb];
    w1y[j] = W1[2 * 64 + ha];   w1y[8 + j] = W1[2 * 64 + hb];
    // edge_raw[3] == 1 -> fold W1 row 3 into bias
    b1p[j]     = b1[ha] + W1[3 * 64 + ha];
    b1p[8 + j] = b1[hb] + W1[3 * 64 + hb];
  }

  // W2 B-frags (bf16): B[k = half*32 + quad*8 + j][col = c*16 + l15]
  bf16x8 Bfrag[4][2];
#pragma unroll
  for (int c = 0; c < 4; ++c) {
#pragma unroll
    for (int h = 0; h < 2; ++h) {
      bf16x8 f;
#pragma unroll
      for (int j = 0; j < 8; ++j) {
        const int k = h * 32 + quad * 8 + j;
        f[j] = to_bf16_rne(W2[k * 64 + c * 16 + l15]);
      }
      Bfrag[c][h] = f;
    }
  }

  // b2 folded into sigmoid exp-arg: arg = e*NL2E + NL2E*b2[h2]
  float b2c[4];
#pragma unroll
  for (int c = 0; c < 4; ++c) b2c[c] = NL2E * b2[c * 16 + l15];

  // stage h_r chunk + x_r/r_p chunk
  for (int idx = tid; idx < MCHUNK * 64; idx += 256) {
    const int mm = idx >> 6, hh = idx & 63;
    hr_s[mm][hh] = h_r[(mBase + mm) * 64 + hh];
  }
  for (int idx = tid; idx < MCHUNK * 8; idx += 256) {
    const int mm = idx >> 3, k = idx & 7;
    float v = 0.f;
    const int m = mBase + mm;
    if (k < 3)      v = x_r[m * 3 + k];
    else if (k < 6) v = h_r[m * 64 + 61 + (k - 3)];
    xr_s[mm][k] = v;
  }

  const f32x4 zero4 = {0.f, 0.f, 0.f, 0.f};
  float numr[4][4], denr[4][4];
#pragma unroll
  for (int c = 0; c < 4; ++c)
#pragma unroll
    for (int r = 0; r < 4; ++r) { numr[c][r] = 0.f; denr[c][r] = 0.f; }

  __syncthreads();

#pragma unroll 1
  for (int ms = 0; ms < MCHUNK; ++ms) {
    // broadcast per-m values
    const float xr0 = xr_s[ms][0], xr1 = xr_s[ms][1], xr2 = xr_s[ms][2];
    const float rp0 = xr_s[ms][3], rp1 = xr_s[ms][4], rp2 = xr_s[ms][5];
    const float dx = xl0 - xr0, dy = xl1 - xr1, dz = xl2 - xr2;
    const float d2 = fmaf(dz, dz, fmaf(dy, dy, dx * dx));
    const float dist = fast_exp2(d2 * C1E);          // exp(-d2/5)
    const float hb = fmaf(lp1, rp0, lp0 * rp1);
    const float hy = lp2 * rp2;

    // layer 1 + silu, directly in A-frag element order
    float s[16];
#pragma unroll
    for (int j = 0; j < 16; ++j) {
      const float t = fmaf(dist, w1d[j], fmaf(hb, w1h[j], fmaf(hy, w1y[j], b1p[j])));
      s[j] = t * fast_rcp(1.0f + fast_exp2(t * NL2E));  // silu
    }
    i32x4 p0, p1;
    p0.x = pack_bf16_rn(s[0], s[1]);   p0.y = pack_bf16_rn(s[2], s[3]);
    p0.z = pack_bf16_rn(s[4], s[5]);   p0.w = pack_bf16_rn(s[6], s[7]);
    p1.x = pack_bf16_rn(s[8], s[9]);   p1.y = pack_bf16_rn(s[10], s[11]);
    p1.z = pack_bf16_rn(s[12], s[13]); p1.w = pack_bf16_rn(s[14], s[15]);
    const bf16x8 A0 = __builtin_bit_cast(bf16x8, p0);
    const bf16x8 A1 = __builtin_bit_cast(bf16x8, p1);

    f32x4 acc[4];
#pragma unroll
    for (int c = 0; c < 4; ++c) {
      acc[c] = __builtin_amdgcn_mfma_f32_16x16x32_bf16(A0, Bfrag[c][0], zero4, 0, 0, 0);
      acc[c] = __builtin_amdgcn_mfma_f32_16x16x32_bf16(A1, Bfrag[c][1], acc[c], 0, 0, 0);
    }

    // sigmoid + accumulate: lane holds e[n = n0+quad*4+r][h2 = c*16+l15]
#pragma unroll
    for (int c = 0; c < 4; ++c) {
      const float hrv = hr_s[ms][c * 16 + l15];
#pragma unroll
      for (int r = 0; r < 4; ++r) {
        const float w = fast_rcp(1.0f + fast_exp2(fmaf(acc[c][r], NL2E, b2c[c])));
        numr[c][r] = fmaf(w, hrv, numr[c][r]);
        denr[c][r] += w;
      }
    }
  }

#pragma unroll
  for (int c = 0; c < 4; ++c)
#pragma unroll
    for (int r = 0; r < 4; ++r) {
      const int n = n0 + quad * 4 + r;
      const int h2 = c * 16 + l15;
      atomicAdd(&num_g[n * 64 + h2], numr[c][r]);
      atomicAdd(&den_g[n * 64 + h2], denr[c][r]);
    }
}

// ---------------------------------------------------------------------------
// Node phase: one wave per row. h_agg = num/(den+1e-6); z = cat(h_l,h_agg)@Wn1
// + bn1 -> LN -> silu -> @Wn2 + bn2; out = h_l + z.
// ---------------------------------------------------------------------------
__global__ __launch_bounds__(256)
void node_kernel(const float* __restrict__ h_l,
                 const float* __restrict__ num_g,
                 const float* __restrict__ den_g,
                 const float* __restrict__ Wn1,
                 const float* __restrict__ bn1,
                 const float* __restrict__ ln_g,
                 const float* __restrict__ ln_b,
                 const float* __restrict__ Wn2,
                 const float* __restrict__ bn2,
                 float* __restrict__ out) {
  __shared__ float Wn1_s[128 * 64];
  __shared__ float Wn2_s[64 * 64];
  __shared__ float xbuf[4][128];
  __shared__ float zbuf[4][64];

  const int tid = threadIdx.x;
  for (int i = tid; i < 128 * 64; i += 256) Wn1_s[i] = Wn1[i];
  for (int i = tid; i < 64 * 64; i += 256) Wn2_s[i] = Wn2[i];

  const int wave = tid >> 6, lane = tid & 63;
  const int row = blockIdx.x * 4 + wave;

  const float hl = h_l[row * 64 + lane];
  const float dn = den_g[row * 64 + lane] + 1e-6f;
  const float hagg = num_g[row * 64 + lane] * fast_rcp(dn);
  xbuf[wave][lane] = hl;
  xbuf[wave][64 + lane] = hagg;
  __syncthreads();

  float t = bn1[lane];
#pragma unroll 8
  for (int k = 0; k < 128; ++k) t = fmaf(xbuf[wave][k], Wn1_s[k * 64 + lane], t);

  float s1 = t, s2 = t * t;
#pragma unroll
  for (int off = 32; off; off >>= 1) {
    s1 += __shfl_xor(s1, off);
    s2 += __shfl_xor(s2, off);
  }
  const float mu = s1 * 0.015625f;
  const float var = fmaf(s2, 0.015625f, -mu * mu);
  const float rs = fast_rsq(var + 1e-5f);
  const float zn = fmaf((t - mu) * rs, ln_g[lane], ln_b[lane]);
  const float sz = zn * fast_rcp(1.0f + fast_exp2(zn * NL2E));  // silu
  zbuf[wave][lane] = sz;
  __syncthreads();

  float o = bn2[lane];
#pragma unroll 8
  for (int k = 0; k < 64; ++k) o = fmaf(zbuf[wave][k], Wn2_s[k * 64 + lane], o);

  out[row * 64 + lane] = hl + o;
}

extern "C" void kernel_launch(void* const* d_in, const int* in_sizes, int n_in,
                              void* d_out, int out_size, void* d_ws, size_t ws_size,
                              hipStream_t stream) {
  const float* h_l = (const float*)d_in[0];
  const float* x_l = (const float*)d_in[1];
  const float* h_r = (const float*)d_in[2];
  const float* x_r = (const float*)d_in[3];
  const float* W1  = (const float*)d_in[4];
  const float* b1  = (const float*)d_in[5];
  const float* W2  = (const float*)d_in[6];
  const float* b2  = (const float*)d_in[7];
  const float* Wn1 = (const float*)d_in[8];
  const float* bn1 = (const float*)d_in[9];
  const float* lng = (const float*)d_in[10];
  const float* lnb = (const float*)d_in[11];
  const float* Wn2 = (const float*)d_in[12];
  const float* bn2 = (const float*)d_in[13];

  float* num_g = (float*)d_ws;
  float* den_g = num_g + (size_t)NTOT * 64;

  hipMemsetAsync(d_ws, 0, (size_t)NTOT * 64 * 2 * sizeof(float), stream);
  edge_kernel<<<dim3((NTOT / 64) * MSPLIT), dim3(256), 0, stream>>>(
      h_l, x_l, h_r, x_r, W1, b1, W2, b2, num_g, den_g);
  node_kernel<<<dim3(NTOT / 4), dim3(256), 0, stream>>>(
      h_l, num_g, den_g, Wn1, bn1, lng, lnb, Wn2, bn2, (float*)d_out);
}

// Round 6
// 239.211 us; speedup vs baseline: 2.2637x; 2.2637x over previous
//
#include <hip/hip_runtime.h>
#include <hip/hip_bf16.h>

// INPUTS/OUTPUT ARE FLOAT32 (R1/R3/R4 NaN'd reading them as bf16).
// PERF NOTE (R5): __launch_bounds__(256,4) forced VGPR 96->64 and spilled
// ~50 regs to scratch -> FETCH 514 MB, VALUBusy 30%, 2.6x slowdown.
// Keep (256,2): compiler picks ~96 VGPR, no spills, 4 blocks/CU possible.

#define NTOT 2048
#define MTOT 2048
#define MSPLIT 32
#define MCHUNK 64   // == per-block m range: single staging chunk

typedef short bf16x8 __attribute__((ext_vector_type(8)));
typedef float f32x4  __attribute__((ext_vector_type(4)));
typedef int   i32x4  __attribute__((ext_vector_type(4)));

// exp(x) = 2^(x*log2e); sigmoid(x) = 1/(1+2^(-x*log2e))
#define NL2E (-1.4426950408889634f)
// exp(-d2/5) = 2^(d2 * -log2e/5)
#define C1E  (-0.2885390081777927f)

__device__ __forceinline__ float fast_exp2(float x) {
#if __has_builtin(__builtin_amdgcn_exp2f)
  return __builtin_amdgcn_exp2f(x);
#else
  return __exp2f(x);
#endif
}
__device__ __forceinline__ float fast_rcp(float x) {
#if __has_builtin(__builtin_amdgcn_rcpf)
  return __builtin_amdgcn_rcpf(x);
#else
  return 1.0f / x;
#endif
}
__device__ __forceinline__ float fast_rsq(float x) {
#if __has_builtin(__builtin_amdgcn_rsqf)
  return __builtin_amdgcn_rsqf(x);
#else
  return rsqrtf(x);
#endif
}

// f32 -> bf16 raw bits, round-to-nearest-even (for MFMA B fragments)
__device__ __forceinline__ short to_bf16_rne(float x) {
  union { float f; unsigned u; } v; v.f = x;
  unsigned r = v.u + 0x7FFFu + ((v.u >> 16) & 1u);
  return (short)(r >> 16);
}

// pack two f32 -> two bf16 (round-half-up) in one u32 (lo in low half).
__device__ __forceinline__ unsigned pack_bf16_rn(float lo, float hi) {
  union { float f; unsigned u; } a, b;
  a.f = lo; b.f = hi;
  unsigned au = a.u + 0x8000u, bu = b.u + 0x8000u;
#if __has_builtin(__builtin_amdgcn_perm)
  return __builtin_amdgcn_perm(bu, au, 0x07060302u);
#else
  return (au >> 16) | (bu & 0xffff0000u);
#endif
}

// ---------------------------------------------------------------------------
// Edge phase: per wave, 16 n-rows; loop over this block's 64-m range.
// For each m: edge feats -> 4->64 MLP+silu (VALU, directly in A-frag layout)
// -> 64->64 via 8x mfma_16x16x32_bf16 -> sigmoid -> accumulate num/den in regs
// -> atomicAdd partials. Grid: (NTOT/64) * MSPLIT = 1024 blocks of 256.
// ---------------------------------------------------------------------------
__global__ __launch_bounds__(256, 2)
void edge_kernel(const float* __restrict__ h_l,
                 const float* __restrict__ x_l,
                 const float* __restrict__ h_r,
                 const float* __restrict__ x_r,
                 const float* __restrict__ W1,
                 const float* __restrict__ b1,
                 const float* __restrict__ W2,
                 const float* __restrict__ b2,
                 float* __restrict__ num_g,
                 float* __restrict__ den_g) {
  __shared__ float hr_s[MCHUNK][64];  // h_r chunk (16 KB)
  __shared__ float xr_s[MCHUNK][8];   // x_r(3), r_p(3), pad (2 KB)

  const int tid  = threadIdx.x;
  const int wave = tid >> 6;
  const int lane = tid & 63;
  const int l15  = lane & 15;
  const int quad = lane >> 4;

  const int nblk   = blockIdx.x / MSPLIT;
  const int msplit = blockIdx.x % MSPLIT;
  const int n0     = nblk * 64 + wave * 16;
  const int mBase  = msplit * MCHUNK;

  // per-lane A-row n
  const int nA = n0 + l15;
  const float xl0 = x_l[nA * 3 + 0];
  const float xl1 = x_l[nA * 3 + 1];
  const float xl2 = x_l[nA * 3 + 2];
  const float lp0 = h_l[nA * 64 + 61];
  const float lp1 = h_l[nA * 64 + 62];
  const float lp2 = h_l[nA * 64 + 63];

  // layer-1 weights for this lane's 16 h1 columns (h1 = quad*8+j and 32+quad*8+j)
  float w1d[16], w1h[16], w1y[16], b1p[16];
#pragma unroll
  for (int j = 0; j < 8; ++j) {
    const int ha = quad * 8 + j, hb = 32 + quad * 8 + j;
    w1d[j] = W1[0 * 64 + ha];   w1d[8 + j] = W1[0 * 64 + hb];
    w1h[j] = W1[1 * 64 + ha];   w1h[8 + j] = W1[1 * 64 + hb];
    w1y[j] = W1[2 * 64 + ha];   w1y[8 + j] = W1[2 * 64 + hb];
    // edge_raw[3] == 1 -> fold W1 row 3 into bias
    b1p[j]     = b1[ha] + W1[3 * 64 + ha];
    b1p[8 + j] = b1[hb] + W1[3 * 64 + hb];
  }

  // W2 B-frags (bf16): B[k = half*32 + quad*8 + j][col = c*16 + l15]
  bf16x8 Bfrag[4][2];
#pragma unroll
  for (int c = 0; c < 4; ++c) {
#pragma unroll
    for (int h = 0; h < 2; ++h) {
      bf16x8 f;
#pragma unroll
      for (int j = 0; j < 8; ++j) {
        const int k = h * 32 + quad * 8 + j;
        f[j] = to_bf16_rne(W2[k * 64 + c * 16 + l15]);
      }
      Bfrag[c][h] = f;
    }
  }

  // b2 folded into sigmoid exp-arg: arg = e*NL2E + NL2E*b2[h2]
  float b2c[4];
#pragma unroll
  for (int c = 0; c < 4; ++c) b2c[c] = NL2E * b2[c * 16 + l15];

  // stage h_r chunk + x_r/r_p chunk
  for (int idx = tid; idx < MCHUNK * 64; idx += 256) {
    const int mm = idx >> 6, hh = idx & 63;
    hr_s[mm][hh] = h_r[(mBase + mm) * 64 + hh];
  }
  for (int idx = tid; idx < MCHUNK * 8; idx += 256) {
    const int mm = idx >> 3, k = idx & 7;
    float v = 0.f;
    const int m = mBase + mm;
    if (k < 3)      v = x_r[m * 3 + k];
    else if (k < 6) v = h_r[m * 64 + 61 + (k - 3)];
    xr_s[mm][k] = v;
  }

  const f32x4 zero4 = {0.f, 0.f, 0.f, 0.f};
  float numr[4][4], denr[4][4];
#pragma unroll
  for (int c = 0; c < 4; ++c)
#pragma unroll
    for (int r = 0; r < 4; ++r) { numr[c][r] = 0.f; denr[c][r] = 0.f; }

  __syncthreads();

#pragma unroll 1
  for (int ms = 0; ms < MCHUNK; ++ms) {
    // broadcast per-m values
    const float xr0 = xr_s[ms][0], xr1 = xr_s[ms][1], xr2 = xr_s[ms][2];
    const float rp0 = xr_s[ms][3], rp1 = xr_s[ms][4], rp2 = xr_s[ms][5];
    const float dx = xl0 - xr0, dy = xl1 - xr1, dz = xl2 - xr2;
    const float d2 = fmaf(dz, dz, fmaf(dy, dy, dx * dx));
    const float dist = fast_exp2(d2 * C1E);          // exp(-d2/5)
    const float hb = fmaf(lp1, rp0, lp0 * rp1);
    const float hy = lp2 * rp2;

    // layer 1 + silu, directly in A-frag element order
    float s[16];
#pragma unroll
    for (int j = 0; j < 16; ++j) {
      const float t = fmaf(dist, w1d[j], fmaf(hb, w1h[j], fmaf(hy, w1y[j], b1p[j])));
      s[j] = t * fast_rcp(1.0f + fast_exp2(t * NL2E));  // silu
    }
    i32x4 p0, p1;
    p0.x = pack_bf16_rn(s[0], s[1]);   p0.y = pack_bf16_rn(s[2], s[3]);
    p0.z = pack_bf16_rn(s[4], s[5]);   p0.w = pack_bf16_rn(s[6], s[7]);
    p1.x = pack_bf16_rn(s[8], s[9]);   p1.y = pack_bf16_rn(s[10], s[11]);
    p1.z = pack_bf16_rn(s[12], s[13]); p1.w = pack_bf16_rn(s[14], s[15]);
    const bf16x8 A0 = __builtin_bit_cast(bf16x8, p0);
    const bf16x8 A1 = __builtin_bit_cast(bf16x8, p1);

    f32x4 acc[4];
#pragma unroll
    for (int c = 0; c < 4; ++c) {
      acc[c] = __builtin_amdgcn_mfma_f32_16x16x32_bf16(A0, Bfrag[c][0], zero4, 0, 0, 0);
      acc[c] = __builtin_amdgcn_mfma_f32_16x16x32_bf16(A1, Bfrag[c][1], acc[c], 0, 0, 0);
    }

    // sigmoid + accumulate: lane holds e[n = n0+quad*4+r][h2 = c*16+l15]
#pragma unroll
    for (int c = 0; c < 4; ++c) {
      const float hrv = hr_s[ms][c * 16 + l15];
#pragma unroll
      for (int r = 0; r < 4; ++r) {
        const float w = fast_rcp(1.0f + fast_exp2(fmaf(acc[c][r], NL2E, b2c[c])));
        numr[c][r] = fmaf(w, hrv, numr[c][r]);
        denr[c][r] += w;
      }
    }
  }

#pragma unroll
  for (int c = 0; c < 4; ++c)
#pragma unroll
    for (int r = 0; r < 4; ++r) {
      const int n = n0 + quad * 4 + r;
      const int h2 = c * 16 + l15;
      atomicAdd(&num_g[n * 64 + h2], numr[c][r]);
      atomicAdd(&den_g[n * 64 + h2], denr[c][r]);
    }
}

// ---------------------------------------------------------------------------
// Node phase: one wave per row. h_agg = num/(den+1e-6); z = cat(h_l,h_agg)@Wn1
// + bn1 -> LN -> silu -> @Wn2 + bn2; out = h_l + z.
// ---------------------------------------------------------------------------
__global__ __launch_bounds__(256)
void node_kernel(const float* __restrict__ h_l,
                 const float* __restrict__ num_g,
                 const float* __restrict__ den_g,
                 const float* __restrict__ Wn1,
                 const float* __restrict__ bn1,
                 const float* __restrict__ ln_g,
                 const float* __restrict__ ln_b,
                 const float* __restrict__ Wn2,
                 const float* __restrict__ bn2,
                 float* __restrict__ out) {
  __shared__ float Wn1_s[128 * 64];
  __shared__ float Wn2_s[64 * 64];
  __shared__ float xbuf[4][128];
  __shared__ float zbuf[4][64];

  const int tid = threadIdx.x;
  for (int i = tid; i < 128 * 64; i += 256) Wn1_s[i] = Wn1[i];
  for (int i = tid; i < 64 * 64; i += 256) Wn2_s[i] = Wn2[i];

  const int wave = tid >> 6, lane = tid & 63;
  const int row = blockIdx.x * 4 + wave;

  const float hl = h_l[row * 64 + lane];
  const float dn = den_g[row * 64 + lane] + 1e-6f;
  const float hagg = num_g[row * 64 + lane] * fast_rcp(dn);
  xbuf[wave][lane] = hl;
  xbuf[wave][64 + lane] = hagg;
  __syncthreads();

  float t = bn1[lane];
#pragma unroll 8
  for (int k = 0; k < 128; ++k) t = fmaf(xbuf[wave][k], Wn1_s[k * 64 + lane], t);

  float s1 = t, s2 = t * t;
#pragma unroll
  for (int off = 32; off; off >>= 1) {
    s1 += __shfl_xor(s1, off);
    s2 += __shfl_xor(s2, off);
  }
  const float mu = s1 * 0.015625f;
  const float var = fmaf(s2, 0.015625f, -mu * mu);
  const float rs = fast_rsq(var + 1e-5f);
  const float zn = fmaf((t - mu) * rs, ln_g[lane], ln_b[lane]);
  const float sz = zn * fast_rcp(1.0f + fast_exp2(zn * NL2E));  // silu
  zbuf[wave][lane] = sz;
  __syncthreads();

  float o = bn2[lane];
#pragma unroll 8
  for (int k = 0; k < 64; ++k) o = fmaf(zbuf[wave][k], Wn2_s[k * 64 + lane], o);

  out[row * 64 + lane] = hl + o;
}

extern "C" void kernel_launch(void* const* d_in, const int* in_sizes, int n_in,
                              void* d_out, int out_size, void* d_ws, size_t ws_size,
                              hipStream_t stream) {
  const float* h_l = (const float*)d_in[0];
  const float* x_l = (const float*)d_in[1];
  const float* h_r = (const float*)d_in[2];
  const float* x_r = (const float*)d_in[3];
  const float* W1  = (const float*)d_in[4];
  const float* b1  = (const float*)d_in[5];
  const float* W2  = (const float*)d_in[6];
  const float* b2  = (const float*)d_in[7];
  const float* Wn1 = (const float*)d_in[8];
  const float* bn1 = (const float*)d_in[9];
  const float* lng = (const float*)d_in[10];
  const float* lnb = (const float*)d_in[11];
  const float* Wn2 = (const float*)d_in[12];
  const float* bn2 = (const float*)d_in[13];

  float* num_g = (float*)d_ws;
  float* den_g = num_g + (size_t)NTOT * 64;

  hipMemsetAsync(d_ws, 0, (size_t)NTOT * 64 * 2 * sizeof(float), stream);
  edge_kernel<<<dim3((NTOT / 64) * MSPLIT), dim3(256), 0, stream>>>(
      h_l, x_l, h_r, x_r, W1, b1, W2, b2, num_g, den_g);
  node_kernel<<<dim3(NTOT / 4), dim3(256), 0, stream>>>(
      h_l, num_g, den_g, Wn1, bn1, lng, lnb, Wn2, bn2, (float*)d_out);
}